// Round 13
// baseline (455.146 us; speedup 1.0000x reference)
//
#include <hip/hip_runtime.h>
#include <math.h>

#define N_NODES   50000
#define N_EDGES   800000
#define NUM_GRAPHS 64
#define FDIM      64
#define HDIM      64
#define NLAYERS   3
#define NCLASSES  16
#define EPS       1e-5f

#define SCAN_CHUNK 1024
#define NCHUNKS ((N_NODES + SCAN_CHUNK - 1) / SCAN_CHUNK)   // 49

typedef unsigned short u16;
typedef unsigned int   u32;
typedef __attribute__((ext_vector_type(8))) short short8;   // 8 bf16 (4 VGPRs)
typedef __attribute__((ext_vector_type(4))) float floatx4;  // MFMA accum

// WkS layout per layer (u16 bf16 bits):
//   [26 kchunk][3 split][4 ntile][16 n][32 k-swizzled] -> 159744 u16 per layer
// K-order: chunks 0-1 = x cols 0..63; then for aggr group j (j=0..7, 32 cols):
//   chunk 2+3j+0 = plain, +1 = amp, +2 = att.
// k position within a chunk row is swizzled: element (n16, kin=qh*8+jj) stored
// at n16*32 + ((qh + (n16>>1)) & 3)*8 + jj  (2-way LDS bank spread on read).
// The L split is written by k_comb but not consumed (3-product scheme).
#define WKS_LAYER 159744
// PreS layout per layer: [2 kchunk][3 split][8 ntile][16 n][32 k-swizzled]
#define PRES_LAYER 24576
// k_post dynamic LDS: H/M splits of one ntile-HALF, fully resident:
//   [26 ch][2 split][2 ntile][512 u16] = 53248 u16 = 104 KB
#define KPOST_LDS_BYTES 106496

// ---------------------------------------------------------------------------
__device__ inline void split1(float f, u16& h, u16& m, u16& l) {
    u32 b  = __float_as_uint(f);
    u32 hb = b & 0xFFFF0000u;
    float r = f - __uint_as_float(hb);
    u32 mb = __float_as_uint(r) & 0xFFFF0000u;
    float r2 = r - __uint_as_float(mb);
    u32 lb = __float_as_uint(r2) & 0xFFFF0000u;
    h = (u16)(hb >> 16); m = (u16)(mb >> 16); l = (u16)(lb >> 16);
}

// async global->LDS DMA, 16B per lane (dest = wave-uniform base + lane*16)
__device__ inline void gl_lds16(const void* g, void* l) {
    __builtin_amdgcn_global_load_lds(
        (const __attribute__((address_space(1))) u32*)g,
        (__attribute__((address_space(3))) u32*)l, 16, 0, 0);
}

// ---------------------------------------------------------------------------
// Weight folding Wk = (lin_w @ post_w) -> 3-way bf16 split (K-permuted,
// swizzled); PreS = pre_w 3-way bf16 split; bc = lin_b + lin_w@post_b.
// Zero-inits cnt/logsum AND g_sum/g_cnt (must precede all accumulation).
__global__ __launch_bounds__(256) void k_comb(const float* __restrict__ post_w,
                                              const float* __restrict__ lin_w,
                                              const float* __restrict__ pre_w,
                                              const float* __restrict__ post_b,
                                              const float* __restrict__ lin_b,
                                              u16* __restrict__ WkS,
                                              u16* __restrict__ PreS,
                                              float* __restrict__ bcv,
                                              int* __restrict__ cnt,
                                              float* __restrict__ logsum,
                                              float* __restrict__ g_sum,
                                              int* __restrict__ g_cnt) {
    int b = blockIdx.x, t = threadIdx.x;
    int zi = b * 256 + t;
    if (zi < N_NODES) cnt[zi] = 0;
    if (zi == 0) *logsum = 0.f;
    if (zi < 4096) g_sum[zi] = 0.f;
    if (zi < 64)   g_cnt[zi] = 0;

    if (b < 624) {
        int c  = t & 63;
        int kl = t >> 6;
        int l  = b / 208;
        int o  = (b % 208) * 4 + kl;          // original K column in [0,832)
        const float* lw = lin_w + (size_t)l * 4096 + c * 64;
        const float* pw = post_w + (size_t)l * 53248 + o;
        float acc = 0.f;
        #pragma unroll 8
        for (int j = 0; j < 64; ++j)
            acc += lw[j] * pw[(size_t)j * 832];
        u16 h, m, lo;
        split1(acc, h, m, lo);

        int kn;
        if (o < 64) kn = o;
        else {
            int s  = (o - 64) >> 8;           // 0 plain, 1 amp, 2 att
            int mm = (o - 64) & 255;
            int j  = mm >> 5, r = mm & 31;
            kn = 64 + j * 96 + s * 32 + r;
        }
        int ch  = kn >> 5;
        int kin = kn & 31;
        int n16 = c & 15, nt = c >> 4;
        int swk = (((kin >> 3) + (n16 >> 1)) & 3) * 8 + (kin & 7);
        size_t base = (size_t)l * WKS_LAYER + (size_t)ch * 6144
                    + nt * 512 + n16 * 32 + swk;
        WkS[base]        = h;
        WkS[base + 2048] = m;
        WkS[base + 4096] = lo;
    } else if (b == 624) {
        if (t < 192) {
            int l = t >> 6, c = t & 63;
            float acc = lin_b[l * 64 + c];
            for (int j = 0; j < 64; ++j)
                acc += lin_w[(size_t)l * 4096 + c * 64 + j] * post_b[l * 64 + j];
            bcv[l * 64 + c] = acc;
        }
    } else {
        int i = (b - 625) * 256 + t;
        int l = i >> 13;
        int rem = i & 8191;
        int c128 = rem >> 6;
        int k = rem & 63;
        float v;
        if (c128 < 64) v = pre_w[(size_t)l * 8192 + c128 * 128 + k];
        else           v = pre_w[(size_t)l * 8192 + (c128 - 64) * 128 + 64 + k];
        u16 h, m, lo;
        split1(v, h, m, lo);
        int ch = k >> 5, kin = k & 31;
        int nt = c128 >> 4, n16 = c128 & 15;
        int swk = (((kin >> 3) + (n16 >> 1)) & 3) * 8 + (kin & 7);
        size_t base = (size_t)l * PRES_LAYER + (size_t)ch * 12288
                    + nt * 512 + n16 * 32 + swk;
        PreS[base]        = h;
        PreS[base + 4096] = m;
        PreS[base + 8192] = lo;
    }
}

// ---------------------------------------------------------------------------
__global__ void k_count(const int* __restrict__ dst, int* __restrict__ cnt,
                        int* __restrict__ rank) {
    int e = blockIdx.x * 256 + threadIdx.x;
    if (e < N_EDGES) rank[e] = atomicAdd(&cnt[dst[e]], 1);
}

__global__ void k_chunk_sums(const int* __restrict__ cnt, int* __restrict__ bsum,
                             float* __restrict__ logsum) {
    __shared__ int   ired[256];
    __shared__ float lred[256];
    int b = blockIdx.x, t = threadIdx.x;
    int base = b * SCAN_CHUNK;
    int s = 0; float ls = 0.f;
    for (int i = t; i < SCAN_CHUNK; i += 256) {
        int idx = base + i;
        if (idx < N_NODES) {
            int v = cnt[idx];
            s += v;
            ls += logf((float)v + 1.0f);
        }
    }
    ired[t] = s; lred[t] = ls;
    __syncthreads();
    for (int off = 128; off > 0; off >>= 1) {
        if (t < off) { ired[t] += ired[t + off]; lred[t] += lred[t + off]; }
        __syncthreads();
    }
    if (t == 0) { bsum[b] = ired[0]; atomicAdd(logsum, lred[0]); }
}

// ---------------------------------------------------------------------------
// k_scan2 (R13): fuses k_scan_top + k_scan_chunks + k_scal + g_cnt counting.
// Each block: serial wave-uniform prefix of bsum[0..b) (<=48 scalar loads),
// coalesced chunk scan (proven pattern), row_start + degree-scaler writes,
// and run-accumulated g_cnt from sorted batch (~1 atomic per thread-run).
// g_cnt was zeroed in k_comb (strictly earlier kernel -> no race).
__global__ __launch_bounds__(256) void k_scan2(const int* __restrict__ cnt,
                                               const int* __restrict__ bsum,
                                               const float* __restrict__ logsum,
                                               const int* __restrict__ batch,
                                               int* __restrict__ row_start,
                                               float* __restrict__ inv_deg,
                                               float* __restrict__ ampv,
                                               float* __restrict__ attv,
                                               int* __restrict__ g_cnt) {
    __shared__ int tsum[256];
    int b = blockIdx.x, t = threadIdx.x;

    int boffb = 0;
    for (int i = 0; i < b; ++i) boffb += bsum[i];   // wave-uniform scalar loop

    int base = b * SCAN_CHUNK + t * 4;
    int v[4]; int s = 0;
    #pragma unroll
    for (int i = 0; i < 4; ++i) {
        int idx = base + i;
        v[i] = (idx < N_NODES) ? cnt[idx] : 0;
        s += v[i];
    }
    tsum[t] = s;
    __syncthreads();
    for (int off = 1; off < 256; off <<= 1) {
        int val = (t >= off) ? tsum[t - off] : 0;
        __syncthreads();
        tsum[t] += val;
        __syncthreads();
    }
    int excl = boffb + tsum[t] - s;
    float avg = logsum[0] / (float)N_NODES;

    int curb = -1, c = 0;
    #pragma unroll
    for (int i = 0; i < 4; ++i) {
        int idx = base + i;
        if (idx < N_NODES) {
            row_start[idx] = excl;
            excl += v[i];
            float degf = fmaxf((float)v[i], 1.0f);
            inv_deg[idx] = 1.0f / degf;
            float ld = logf(degf + 1.0f);
            ampv[idx] = ld / avg;
            attv[idx] = avg / ld;
            int bb = batch[idx];
            if (bb != curb) {
                if (c) atomicAdd(&g_cnt[curb], c);
                curb = bb; c = 0;
            }
            ++c;
        }
    }
    if (c) atomicAdd(&g_cnt[curb], c);
    if (b == 0 && t == 0) row_start[N_NODES] = N_EDGES;
}

// atomic-free scatter: slot = row_start[dst] + rank (plain writes, L2-coalesced)
__global__ void k_scatter(const int* __restrict__ src, const int* __restrict__ dst,
                          const int* __restrict__ rank,
                          const int* __restrict__ row_start,
                          int* __restrict__ csr_src) {
    int e = blockIdx.x * 256 + threadIdx.x;
    if (e < N_EDGES) {
        int d = dst[e];
        csr_src[row_start[d] + rank[e]] = src[e];
    }
}

// ---------------------------------------------------------------------------
// MFMA k_pre (3-product split, passing R10 version)
__global__ __launch_bounds__(256, 4) void k_pre(const float* __restrict__ x,
                                                const u16* __restrict__ PreS,
                                                const float* __restrict__ pre_b,
                                                float* __restrict__ p,
                                                float* __restrict__ q) {
    __shared__ u16 ldsB[2 * 8192];   // [2 ch][2 sp][8 nt][512 u16] = 32 KB
    int t = threadIdx.x;
    int w = t >> 6;
    int lane = t & 63;
    int m = lane & 15;
    int qh = lane >> 4;
    int rowBase = blockIdx.x * 64;

    int myrow = rowBase + 16 * w + m;
    bool vr = myrow < N_NODES;
    int crow = vr ? myrow : 0;
    const float* xrow = x + (size_t)crow * 64;

    int bo = m * 32 + ((qh + (m >> 1)) & 3) * 8;

    // stage H/M splits: 32 x 1KB units; unit u: ch=u>>4, sp=(u>>3)&1, nt=u&7
    for (int u = w; u < 32; u += 4) {
        int ch = u >> 4, sp = (u >> 3) & 1, nt = u & 7;
        const char* g = (const char*)PreS + (size_t)ch * 24576 + sp * 8192
                      + nt * 1024 + lane * 16;
        char* l = (char*)ldsB + u * 1024;
        gl_lds16(g, l);
    }
    // A: both 32-col chunks of this lane's row (unconditional, clamped row)
    float fa[2][8];
    #pragma unroll
    for (int ch = 0; ch < 2; ++ch) {
        const float* sp = xrow + ch * 32 + qh * 8;
        float4 u0 = *(const float4*)sp;
        float4 u1 = *(const float4*)(sp + 4);
        fa[ch][0] = vr ? u0.x : 0.f; fa[ch][1] = vr ? u0.y : 0.f;
        fa[ch][2] = vr ? u0.z : 0.f; fa[ch][3] = vr ? u0.w : 0.f;
        fa[ch][4] = vr ? u1.x : 0.f; fa[ch][5] = vr ? u1.y : 0.f;
        fa[ch][6] = vr ? u1.z : 0.f; fa[ch][7] = vr ? u1.w : 0.f;
    }
    asm volatile("s_waitcnt vmcnt(0)" ::: "memory");
    __syncthreads();

    floatx4 acc[8] = {};
    #pragma unroll
    for (int ch = 0; ch < 2; ++ch) {
        union { u32 u[4]; short8 s8; } AH, AM;
        #pragma unroll
        for (int i = 0; i < 4; ++i) {
            float f0 = fa[ch][2 * i], f1 = fa[ch][2 * i + 1];
            u32 b0 = __float_as_uint(f0), b1 = __float_as_uint(f1);
            u32 h0 = b0 & 0xFFFF0000u,  h1 = b1 & 0xFFFF0000u;
            float r0 = f0 - __uint_as_float(h0);
            float r1 = f1 - __uint_as_float(h1);
            u32 m0 = __float_as_uint(r0) & 0xFFFF0000u;
            u32 m1 = __float_as_uint(r1) & 0xFFFF0000u;
            AH.u[i] = (h0 >> 16) | h1;
            AM.u[i] = (m0 >> 16) | m1;
        }
        const u16* Bb = ldsB + ch * 8192;
        #pragma unroll
        for (int nt = 0; nt < 8; ++nt) {
            short8 bH = *(const short8*)(Bb + nt * 512 + bo);
            short8 bM = *(const short8*)(Bb + 4096 + nt * 512 + bo);
            acc[nt] = __builtin_amdgcn_mfma_f32_16x16x32_bf16(AH.s8, bH, acc[nt], 0, 0, 0);
            acc[nt] = __builtin_amdgcn_mfma_f32_16x16x32_bf16(AH.s8, bM, acc[nt], 0, 0, 0);
            acc[nt] = __builtin_amdgcn_mfma_f32_16x16x32_bf16(AM.s8, bH, acc[nt], 0, 0, 0);
        }
    }

    int col = m;
    #pragma unroll
    for (int nt = 0; nt < 8; ++nt) {
        int cbase = (nt & 3) * 16 + col;
        float bias = (nt < 4) ? pre_b[cbase] : 0.f;
        float* outp = (nt < 4) ? p : q;
        #pragma unroll
        for (int reg = 0; reg < 4; ++reg) {
            int grow = rowBase + 16 * w + qh * 4 + reg;
            if (grow < N_NODES)
                outp[(size_t)grow * 64 + cbase] = acc[nt][reg] + bias;
        }
    }
}

// ---------------------------------------------------------------------------
// Aggregation (unchanged, passing)
__global__ __launch_bounds__(256) void k_aggr(const float* __restrict__ p,
                                              const float* __restrict__ q,
                                              const int* __restrict__ row_start,
                                              const int* __restrict__ csr_src,
                                              const float* __restrict__ inv_deg,
                                              float* __restrict__ aggr) {
    int wid  = (blockIdx.x * 256 + threadIdx.x) >> 6;
    int lane = threadIdx.x & 63;
    if (wid >= N_NODES) return;
    int n = wid;
    int beg = row_start[n], end = row_start[n + 1];
    float sum = 0.f, sq = 0.f;
    float mn = INFINITY, mx = -INFINITY;
    int e = beg;
    for (; e + 7 < end; e += 8) {
        float qv[8];
        #pragma unroll
        for (int u = 0; u < 8; ++u) {
            int s = csr_src[e + u];
            qv[u] = q[(size_t)s * 64 + lane];
        }
        #pragma unroll
        for (int u = 0; u < 8; ++u) {
            float m = qv[u];
            sum += m; sq += m * m;
            mn = fminf(mn, m); mx = fmaxf(mx, m);
        }
    }
    for (; e + 3 < end; e += 4) {
        float qv[4];
        #pragma unroll
        for (int u = 0; u < 4; ++u) {
            int s = csr_src[e + u];
            qv[u] = q[(size_t)s * 64 + lane];
        }
        #pragma unroll
        for (int u = 0; u < 4; ++u) {
            float m = qv[u];
            sum += m; sq += m * m;
            mn = fminf(mn, m); mx = fmaxf(mx, m);
        }
    }
    for (; e < end; ++e) {
        int s = csr_src[e];
        float m = q[(size_t)s * 64 + lane];
        sum += m; sq += m * m;
        mn = fminf(mn, m); mx = fmaxf(mx, m);
    }
    float* a = aggr + (size_t)n * 256;
    if (end <= beg) {
        a[lane]       = 0.f;
        a[64 + lane]  = 0.f;
        a[128 + lane] = 0.f;
        a[192 + lane] = sqrtf(EPS);
    } else {
        float pv = p[n * 64 + lane];
        float id = inv_deg[n];
        float meanq = sum * id;
        float var = fmaxf(sq * id - meanq * meanq, 0.f);
        a[lane]       = pv + meanq;
        a[64 + lane]  = pv + mn;
        a[128 + lane] = pv + mx;
        a[192 + lane] = sqrtf(var + EPS);
    }
}

// ---------------------------------------------------------------------------
// MFMA k_post (R13): persistent-LDS N-split, 3-product, XCD pair swizzle
// (R12 structure, passing) + OPTIONAL fused pooling: when batch != nullptr
// (last layer), the epilogue skips the xout store and run-accumulates the
// ReLU'd outputs into g_sum per graph (rows monotonic per thread, batch
// sorted -> ~1-2 atomicAdds per thread across 4096 slots). Eliminates
// k_pool and the 25.6 MB xout round-trip.
// LDS: [26 ch][2 split][2 ntile][512 u16] = 106496 B.
__global__ __launch_bounds__(1024, 4) void k_post(const float* __restrict__ x,
                                                  const float* __restrict__ aggr,
                                                  const float* __restrict__ ampv,
                                                  const float* __restrict__ attv,
                                                  const u16* __restrict__ WkS,
                                                  const float* __restrict__ bc,
                                                  float* __restrict__ xout,
                                                  const int* __restrict__ batch,
                                                  float* __restrict__ g_sum) {
    extern __shared__ u16 ldsB[];
    int t = threadIdx.x;
    int w = t >> 6;                 // wave 0..15
    int lane = t & 63;
    int m = lane & 15;
    int qh = lane >> 4;

    // pair swizzle: b = s + 8*(2*q2 + nh); r = 8*q2 + s; both nh share b%8
    int b  = blockIdx.x;
    int s8 = b & 7;
    int g  = b >> 3;
    int q2 = g >> 1;
    int nh = g & 1;                 // ntile half: 0 -> cols 0..31, 1 -> 32..63
    int r  = 8 * q2 + s8;
    if (r >= 98) return;            // 98 = ceil(N_NODES/512); 12 idle blocks
    int rowBase = r * 512 + 32 * w;

    // ---- stage H/M splits of this half: 104 x 1KB units ----
    for (int u = w; u < 104; u += 16) {
        int ch = u >> 2;
        int sp = (u >> 1) & 1;
        int h2 = u & 1;
        const char* gp = (const char*)WkS + ch * 12288 + sp * 4096
                       + nh * 2048 + h2 * 1024 + lane * 16;
        char* l = (char*)ldsB + u * 1024;
        gl_lds16(gp, l);
    }

    int row0 = rowBase + m;
    int row1 = row0 + 16;
    int cr0 = (row0 < N_NODES) ? row0 : 0;
    int cr1 = (row1 < N_NODES) ? row1 : 0;
    const float* xr0 = x + (size_t)cr0 * 64;
    const float* xr1 = x + (size_t)cr1 * 64;
    const float* ar0 = aggr + (size_t)cr0 * 256;
    const float* ar1 = aggr + (size_t)cr1 * 256;

    int bo = m * 32 + ((qh + (m >> 1)) & 3) * 8;   // u16 offset in 512-block

    floatx4 accP0[2] = {}, accA0[2] = {}, accT0[2] = {};
    floatx4 accP1[2] = {}, accA1[2] = {}, accT1[2] = {};

    float f0[8], f1[8];
    union U8 { u32 u[4]; short8 s8v; };
    U8 AH0, AM0, AH1, AM1;

    auto loadRaw = [&](const float* sp, float* f) {
        float4 u0 = *(const float4*)(sp + qh * 8);
        float4 u1 = *(const float4*)(sp + qh * 8 + 4);
        f[0] = u0.x; f[1] = u0.y; f[2] = u0.z; f[3] = u0.w;
        f[4] = u1.x; f[5] = u1.y; f[6] = u1.z; f[7] = u1.w;
    };
    auto split2 = [&](const float* f, U8& H, U8& M8) {
        #pragma unroll
        for (int i = 0; i < 4; ++i) {
            float v0 = f[2 * i], v1 = f[2 * i + 1];
            u32 b0 = __float_as_uint(v0), b1 = __float_as_uint(v1);
            u32 h0 = b0 & 0xFFFF0000u,  h1 = b1 & 0xFFFF0000u;
            float r0 = v0 - __uint_as_float(h0);
            float r1 = v1 - __uint_as_float(h1);
            u32 m0 = __float_as_uint(r0) & 0xFFFF0000u;
            u32 m1 = __float_as_uint(r1) & 0xFFFF0000u;
            H.u[i]  = (h0 >> 16) | h1;
            M8.u[i] = (m0 >> 16) | m1;
        }
    };
    // one K-chunk: 4 LDS b128 reads + 12 MFMAs; 4 independent chains
    // interleaved so a dependent pair is 4 issues apart.
    #define MF(A, B, C) C = __builtin_amdgcn_mfma_f32_16x16x32_bf16((A).s8v, (B), (C), 0, 0, 0)
    auto chunkMM = [&](int ch, floatx4* A0, floatx4* A1) {
        const u16* pB = ldsB + ch * 2048 + bo;
        short8 bH0 = *(const short8*)(pB);
        short8 bH1 = *(const short8*)(pB + 512);
        short8 bM0 = *(const short8*)(pB + 1024);
        short8 bM1 = *(const short8*)(pB + 1536);
        MF(AH0, bH0, A0[0]); MF(AH1, bH0, A1[0]); MF(AH0, bH1, A0[1]); MF(AH1, bH1, A1[1]);
        MF(AH0, bM0, A0[0]); MF(AH1, bM0, A1[0]); MF(AH0, bM1, A0[1]); MF(AH1, bM1, A1[1]);
        MF(AM0, bH0, A0[0]); MF(AM1, bH0, A1[0]); MF(AM0, bH1, A0[1]); MF(AM1, bH1, A1[1]);
    };

    // A(g0) loads, then drain stage DMAs (+these loads) once, one barrier.
    loadRaw(xr0, f0); loadRaw(xr1, f1);
    asm volatile("s_waitcnt vmcnt(0)" ::: "memory");
    __syncthreads();

    // group 0: x cols 0..31 (chunk 0)
    split2(f0, AH0, AM0); split2(f1, AH1, AM1);
    loadRaw(xr0 + 32, f0); loadRaw(xr1 + 32, f1);   // prefetch group 1
    chunkMM(0, accP0, accP1);
    // group 1: x cols 32..63 (chunk 1)
    split2(f0, AH0, AM0); split2(f1, AH1, AM1);
    loadRaw(ar0, f0); loadRaw(ar1, f1);             // prefetch group 2 (aggr 0)
    chunkMM(1, accP0, accP1);
    // groups 2..9: aggr groups j=0..7, chunks 2+3j (P), +1 (A), +2 (T)
    for (int j = 0; j < 8; ++j) {
        split2(f0, AH0, AM0); split2(f1, AH1, AM1);
        if (j < 7) { loadRaw(ar0 + (j + 1) * 32, f0); loadRaw(ar1 + (j + 1) * 32, f1); }
        int ch = 2 + 3 * j;
        chunkMM(ch,     accP0, accP1);
        chunkMM(ch + 1, accA0, accA1);
        chunkMM(ch + 2, accT0, accT1);
    }
    #undef MF

    // epilogue: out = P + amp[row]*A + att[row]*T + bias, ReLU  (N-split cols)
    int col = m;
    int cb0 = (nh * 2 + 0) * 16 + col;
    int cb1 = (nh * 2 + 1) * 16 + col;
    if (batch == nullptr) {
        #pragma unroll
        for (int frag = 0; frag < 2; ++frag) {
            #pragma unroll
            for (int reg = 0; reg < 4; ++reg) {
                int grow = rowBase + 16 * frag + qh * 4 + reg;
                if (grow < N_NODES) {
                    float av = ampv[grow], tv = attv[grow];
                    #pragma unroll
                    for (int nt = 0; nt < 2; ++nt) {
                        int cbase = nt ? cb1 : cb0;
                        float pv  = frag ? accP1[nt][reg] : accP0[nt][reg];
                        float av2 = frag ? accA1[nt][reg] : accA0[nt][reg];
                        float tv2 = frag ? accT1[nt][reg] : accT0[nt][reg];
                        float v = pv + av * av2 + tv * tv2 + bc[cbase];
                        xout[(size_t)grow * 64 + cbase] = fmaxf(v, 0.f);
                    }
                }
            }
        }
    } else {
        // fused pooling (last layer): run-accumulate over this thread's 8
        // monotonic rows, one atomicAdd pair per batch-run.
        float acc0 = 0.f, acc1 = 0.f;
        int cur = -1;
        float bias0 = bc[cb0], bias1 = bc[cb1];
        #pragma unroll
        for (int frag = 0; frag < 2; ++frag) {
            #pragma unroll
            for (int reg = 0; reg < 4; ++reg) {
                int grow = rowBase + 16 * frag + qh * 4 + reg;
                if (grow < N_NODES) {
                    float av = ampv[grow], tv = attv[grow];
                    float p0 = frag ? accP0[0][reg] * 0.f + accP1[0][reg] : accP0[0][reg];
                    float a0 = frag ? accA1[0][reg] : accA0[0][reg];
                    float t0 = frag ? accT1[0][reg] : accT0[0][reg];
                    float p1 = frag ? accP1[1][reg] : accP0[1][reg];
                    float a1 = frag ? accA1[1][reg] : accA0[1][reg];
                    float t1 = frag ? accT1[1][reg] : accT0[1][reg];
                    float v0 = fmaxf(p0 + av * a0 + tv * t0 + bias0, 0.f);
                    float v1 = fmaxf(p1 + av * a1 + tv * t1 + bias1, 0.f);
                    int bb = batch[grow];
                    if (bb != cur) {
                        if (cur >= 0) {
                            atomicAdd(&g_sum[cur * 64 + cb0], acc0);
                            atomicAdd(&g_sum[cur * 64 + cb1], acc1);
                        }
                        cur = bb; acc0 = 0.f; acc1 = 0.f;
                    }
                    acc0 += v0; acc1 += v1;
                }
            }
        }
        if (cur >= 0) {
            atomicAdd(&g_sum[cur * 64 + cb0], acc0);
            atomicAdd(&g_sum[cur * 64 + cb1], acc1);
        }
    }
}

// ---------------------------------------------------------------------------
__global__ __launch_bounds__(256) void k_mlp(const float* __restrict__ g_sum,
                                             const int* __restrict__ g_cnt,
                                             const float* __restrict__ w1,
                                             const float* __restrict__ b1,
                                             const float* __restrict__ w2,
                                             const float* __restrict__ b2,
                                             float* __restrict__ out) {
    __shared__ float g[64][64];
    __shared__ float h[64][64];
    __shared__ float wT[64][65];
    int t = threadIdx.x;
    for (int idx = t; idx < 4096; idx += 256) {
        int gi = idx >> 6, c = idx & 63;
        float cntf = fmaxf((float)g_cnt[gi], 1.f);
        g[gi][c] = g_sum[idx] / cntf;
    }
    for (int idx = t; idx < 4096; idx += 256) {
        int c = idx >> 6, k = idx & 63;
        wT[k][c] = w1[c * 64 + k];
    }
    __syncthreads();
    for (int idx = t; idx < 4096; idx += 256) {
        int gi = idx >> 6, c = idx & 63;
        float acc = b1[c];
        for (int k = 0; k < 64; ++k) acc += g[gi][k] * wT[k][c];
        h[gi][c] = fmaxf(acc, 0.f);
    }
    __syncthreads();
    for (int idx = t; idx < 64 * NCLASSES; idx += 256) {
        int gi = idx >> 4, c = idx & 15;
        float acc = b2[c];
        for (int k = 0; k < 64; ++k) acc += h[gi][k] * w2[c * 64 + k];
        out[gi * NCLASSES + c] = acc;
    }
}

// ---------------------------------------------------------------------------
extern "C" void kernel_launch(void* const* d_in, const int* in_sizes, int n_in,
                              void* d_out, int out_size, void* d_ws, size_t ws_size,
                              hipStream_t stream) {
    const float* x      = (const float*)d_in[0];
    const int*   ei     = (const int*)d_in[1];
    const int*   batch  = (const int*)d_in[2];
    const float* pre_w  = (const float*)d_in[3];
    const float* pre_b  = (const float*)d_in[4];
    const float* post_w = (const float*)d_in[5];
    const float* post_b = (const float*)d_in[6];
    const float* lin_w  = (const float*)d_in[7];
    const float* lin_b  = (const float*)d_in[8];
    const float* mlp_w1 = (const float*)d_in[9];
    const float* mlp_b1 = (const float*)d_in[10];
    const float* mlp_w2 = (const float*)d_in[11];
    const float* mlp_b2 = (const float*)d_in[12];

    const int* src = ei;
    const int* dst = ei + N_EDGES;

    char* base = (char*)d_ws;
    size_t off = 0;
    auto alloc = [&](size_t bytes) -> void* {
        void* ptr = base + off;
        off += (bytes + 255) & ~(size_t)255;
        return ptr;
    };
    int*   cnt       = (int*)alloc(N_NODES * 4);
    int*   row_start = (int*)alloc((N_NODES + 1) * 4);
    int*   rank      = (int*)alloc(N_EDGES * 4);
    int*   csr_src   = (int*)alloc(N_EDGES * 4);
    int*   bsum      = (int*)alloc(64 * 4);
    float* logsum    = (float*)alloc(16);
    float* inv_deg   = (float*)alloc(N_NODES * 4);
    float* ampv      = (float*)alloc(N_NODES * 4);
    float* attv      = (float*)alloc(N_NODES * 4);
    float* p         = (float*)alloc((size_t)N_NODES * 64 * 4);
    float* q         = (float*)alloc((size_t)N_NODES * 64 * 4);
    float* aggr      = (float*)alloc((size_t)N_NODES * 256 * 4);
    float* xb0       = (float*)alloc((size_t)N_NODES * 64 * 4);
    float* xb1       = (float*)alloc((size_t)N_NODES * 64 * 4);
    float* g_sum     = (float*)alloc(64 * 64 * 4);
    int*   g_cnt     = (int*)alloc(64 * 4);
    u16*   WkS       = (u16*)alloc((size_t)3 * WKS_LAYER * 2);
    u16*   PreS      = (u16*)alloc((size_t)3 * PRES_LAYER * 2);
    float* bcv       = (float*)alloc(3 * 64 * 4);

    // weight folding + pre_w split + workspace/accumulator zero-init
    k_comb<<<721, 256, 0, stream>>>(post_w, lin_w, pre_w, post_b, lin_b,
                                    WkS, PreS, bcv, cnt, logsum, g_sum, g_cnt);

    k_count<<<(N_EDGES + 255) / 256, 256, 0, stream>>>(dst, cnt, rank);
    k_chunk_sums<<<NCHUNKS, 256, 0, stream>>>(cnt, bsum, logsum);
    k_scan2<<<NCHUNKS, 256, 0, stream>>>(cnt, bsum, logsum, batch, row_start,
                                         inv_deg, ampv, attv, g_cnt);
    k_scatter<<<(N_EDGES + 255) / 256, 256, 0, stream>>>(src, dst, rank,
                                                         row_start, csr_src);

    const int PRE_BLOCKS  = (N_NODES + 63) / 64;   // 782
    const int POST_BLOCKS = 208;                    // 2 N-halves x 98 + 12 idle
    const float* xin = x;
    float* bufs[3] = {xb0, xb1, xb0};
    for (int l = 0; l < NLAYERS; ++l) {
        k_pre<<<PRE_BLOCKS, 256, 0, stream>>>(xin, PreS + (size_t)l * PRES_LAYER,
                                              pre_b + l * 64, p, q);
        k_aggr<<<(N_NODES + 3) / 4, 256, 0, stream>>>(p, q, row_start, csr_src,
                                                      inv_deg, aggr);
        float* xo = bufs[l];
        const int* bptr = (l == NLAYERS - 1) ? batch : nullptr;
        k_post<<<POST_BLOCKS, 1024, KPOST_LDS_BYTES, stream>>>(
            xin, aggr, ampv, attv, WkS + (size_t)l * WKS_LAYER,
            bcv + l * 64, xo, bptr, g_sum);
        xin = xo;
    }

    k_mlp<<<1, 256, 0, stream>>>(g_sum, g_cnt, mlp_w1, mlp_b1, mlp_w2, mlp_b2,
                                 (float*)d_out);
}

// Round 14
// 454.350 us; speedup vs baseline: 1.0018x; 1.0018x over previous
//
#include <hip/hip_runtime.h>
#include <math.h>

#define N_NODES   50000
#define N_EDGES   800000
#define NUM_GRAPHS 64
#define FDIM      64
#define HDIM      64
#define NLAYERS   3
#define NCLASSES  16
#define EPS       1e-5f

#define SCAN_CHUNK 1024
#define NCHUNKS ((N_NODES + SCAN_CHUNK - 1) / SCAN_CHUNK)   // 49

typedef unsigned short u16;
typedef unsigned int   u32;
typedef __attribute__((ext_vector_type(8))) short short8;   // 8 bf16 (4 VGPRs)
typedef __attribute__((ext_vector_type(4))) float floatx4;  // MFMA accum

// WkS layout per layer (u16 bf16 bits):
//   [26 kchunk][3 split][4 ntile][16 n][32 k-swizzled] -> 159744 u16 per layer
// K-order: chunks 0-1 = x cols 0..63; then for aggr group j (j=0..7, 32 cols):
//   chunk 2+3j+0 = plain, +1 = amp, +2 = att.
// k position within a chunk row is swizzled: element (n16, kin=qh*8+jj) stored
// at n16*32 + ((qh + (n16>>1)) & 3)*8 + jj  (2-way LDS bank spread on read).
// The L split is written by k_comb but not consumed (3-product scheme).
#define WKS_LAYER 159744
// PreS layout per layer: [2 kchunk][3 split][8 ntile][16 n][32 k-swizzled]
#define PRES_LAYER 24576
// k_post dynamic LDS: H/M splits of one ntile-HALF, fully resident:
//   [26 ch][2 split][2 ntile][512 u16] = 53248 u16 = 104 KB
#define KPOST_LDS_BYTES 106496

// ---------------------------------------------------------------------------
__device__ inline void split1(float f, u16& h, u16& m, u16& l) {
    u32 b  = __float_as_uint(f);
    u32 hb = b & 0xFFFF0000u;
    float r = f - __uint_as_float(hb);
    u32 mb = __float_as_uint(r) & 0xFFFF0000u;
    float r2 = r - __uint_as_float(mb);
    u32 lb = __float_as_uint(r2) & 0xFFFF0000u;
    h = (u16)(hb >> 16); m = (u16)(mb >> 16); l = (u16)(lb >> 16);
}

// async global->LDS DMA, 16B per lane (dest = wave-uniform base + lane*16)
__device__ inline void gl_lds16(const void* g, void* l) {
    __builtin_amdgcn_global_load_lds(
        (const __attribute__((address_space(1))) u32*)g,
        (__attribute__((address_space(3))) u32*)l, 16, 0, 0);
}

// ---------------------------------------------------------------------------
// Weight folding Wk = (lin_w @ post_w) -> 3-way bf16 split (K-permuted,
// swizzled); PreS = pre_w 3-way bf16 split; bc = lin_b + lin_w@post_b.
// Zero-inits cnt/logsum AND g_sum/g_cnt (first kernel -> precedes all
// accumulation; k_scan_chunks counts g_cnt, layer-3 k_post sums g_sum).
__global__ __launch_bounds__(256) void k_comb(const float* __restrict__ post_w,
                                              const float* __restrict__ lin_w,
                                              const float* __restrict__ pre_w,
                                              const float* __restrict__ post_b,
                                              const float* __restrict__ lin_b,
                                              u16* __restrict__ WkS,
                                              u16* __restrict__ PreS,
                                              float* __restrict__ bcv,
                                              int* __restrict__ cnt,
                                              float* __restrict__ logsum,
                                              float* __restrict__ g_sum,
                                              int* __restrict__ g_cnt) {
    int b = blockIdx.x, t = threadIdx.x;
    int zi = b * 256 + t;
    if (zi < N_NODES) cnt[zi] = 0;
    if (zi == 0) *logsum = 0.f;
    if (zi < 4096) g_sum[zi] = 0.f;
    if (zi < 64)   g_cnt[zi] = 0;

    if (b < 624) {
        int c  = t & 63;
        int kl = t >> 6;
        int l  = b / 208;
        int o  = (b % 208) * 4 + kl;          // original K column in [0,832)
        const float* lw = lin_w + (size_t)l * 4096 + c * 64;
        const float* pw = post_w + (size_t)l * 53248 + o;
        float acc = 0.f;
        #pragma unroll 8
        for (int j = 0; j < 64; ++j)
            acc += lw[j] * pw[(size_t)j * 832];
        u16 h, m, lo;
        split1(acc, h, m, lo);

        int kn;
        if (o < 64) kn = o;
        else {
            int s  = (o - 64) >> 8;           // 0 plain, 1 amp, 2 att
            int mm = (o - 64) & 255;
            int j  = mm >> 5, r = mm & 31;
            kn = 64 + j * 96 + s * 32 + r;
        }
        int ch  = kn >> 5;
        int kin = kn & 31;
        int n16 = c & 15, nt = c >> 4;
        int swk = (((kin >> 3) + (n16 >> 1)) & 3) * 8 + (kin & 7);
        size_t base = (size_t)l * WKS_LAYER + (size_t)ch * 6144
                    + nt * 512 + n16 * 32 + swk;
        WkS[base]        = h;
        WkS[base + 2048] = m;
        WkS[base + 4096] = lo;
    } else if (b == 624) {
        if (t < 192) {
            int l = t >> 6, c = t & 63;
            float acc = lin_b[l * 64 + c];
            for (int j = 0; j < 64; ++j)
                acc += lin_w[(size_t)l * 4096 + c * 64 + j] * post_b[l * 64 + j];
            bcv[l * 64 + c] = acc;
        }
    } else {
        int i = (b - 625) * 256 + t;
        int l = i >> 13;
        int rem = i & 8191;
        int c128 = rem >> 6;
        int k = rem & 63;
        float v;
        if (c128 < 64) v = pre_w[(size_t)l * 8192 + c128 * 128 + k];
        else           v = pre_w[(size_t)l * 8192 + (c128 - 64) * 128 + 64 + k];
        u16 h, m, lo;
        split1(v, h, m, lo);
        int ch = k >> 5, kin = k & 31;
        int nt = c128 >> 4, n16 = c128 & 15;
        int swk = (((kin >> 3) + (n16 >> 1)) & 3) * 8 + (kin & 7);
        size_t base = (size_t)l * PRES_LAYER + (size_t)ch * 12288
                    + nt * 512 + n16 * 32 + swk;
        PreS[base]        = h;
        PreS[base + 4096] = m;
        PreS[base + 8192] = lo;
    }
}

// ---------------------------------------------------------------------------
__global__ void k_count(const int* __restrict__ dst, int* __restrict__ cnt,
                        int* __restrict__ rank) {
    int e = blockIdx.x * 256 + threadIdx.x;
    if (e < N_EDGES) rank[e] = atomicAdd(&cnt[dst[e]], 1);
}

__global__ void k_chunk_sums(const int* __restrict__ cnt, int* __restrict__ bsum,
                             float* __restrict__ logsum) {
    __shared__ int   ired[256];
    __shared__ float lred[256];
    int b = blockIdx.x, t = threadIdx.x;
    int base = b * SCAN_CHUNK;
    int s = 0; float ls = 0.f;
    for (int i = t; i < SCAN_CHUNK; i += 256) {
        int idx = base + i;
        if (idx < N_NODES) {
            int v = cnt[idx];
            s += v;
            ls += logf((float)v + 1.0f);
        }
    }
    ired[t] = s; lred[t] = ls;
    __syncthreads();
    for (int off = 128; off > 0; off >>= 1) {
        if (t < off) { ired[t] += ired[t + off]; lred[t] += lred[t + off]; }
        __syncthreads();
    }
    if (t == 0) { bsum[b] = ired[0]; atomicAdd(logsum, lred[0]); }
}

__global__ void k_scan_top(const int* __restrict__ bsum, int* __restrict__ boff,
                           int* __restrict__ row_start) {
    if (threadIdx.x == 0) {
        int acc = 0;
        for (int i = 0; i < NCHUNKS; ++i) { boff[i] = acc; acc += bsum[i]; }
        row_start[N_NODES] = acc;
    }
}

// k_scan_chunks (R14): proven coalesced chunk scan + run-length g_cnt
// counting from sorted batch (each thread owns 4 consecutive nodes ->
// ~1 fire-and-forget atomic per thread; g_cnt zeroed in k_comb).
__global__ void k_scan_chunks(const int* __restrict__ cnt, const int* __restrict__ boff,
                              const int* __restrict__ batch,
                              int* __restrict__ row_start,
                              int* __restrict__ g_cnt) {
    __shared__ int tsum[256];
    int b = blockIdx.x, t = threadIdx.x;
    int base = b * SCAN_CHUNK + t * 4;
    int v[4]; int s = 0;
    #pragma unroll
    for (int i = 0; i < 4; ++i) {
        int idx = base + i;
        v[i] = (idx < N_NODES) ? cnt[idx] : 0;
        s += v[i];
    }
    tsum[t] = s;
    __syncthreads();
    for (int off = 1; off < 256; off <<= 1) {
        int val = (t >= off) ? tsum[t - off] : 0;
        __syncthreads();
        tsum[t] += val;
        __syncthreads();
    }
    int excl = boff[b] + tsum[t] - s;
    int curb = -1, c = 0;
    #pragma unroll
    for (int i = 0; i < 4; ++i) {
        int idx = base + i;
        if (idx < N_NODES) {
            row_start[idx] = excl;
            excl += v[i];
            int bb = batch[idx];
            if (bb != curb) {
                if (c) atomicAdd(&g_cnt[curb], c);
                curb = bb; c = 0;
            }
            ++c;
        }
    }
    if (c) atomicAdd(&g_cnt[curb], c);
}

// atomic-free scatter: slot = row_start[dst] + rank (plain writes, L2-coalesced)
__global__ void k_scatter(const int* __restrict__ src, const int* __restrict__ dst,
                          const int* __restrict__ rank,
                          const int* __restrict__ row_start,
                          int* __restrict__ csr_src) {
    int e = blockIdx.x * 256 + threadIdx.x;
    if (e < N_EDGES) {
        int d = dst[e];
        csr_src[row_start[d] + rank[e]] = src[e];
    }
}

// per-node degree scalers (zeroing moved to k_comb)
__global__ void k_scal(const int* __restrict__ cnt, const float* __restrict__ logsum,
                       float* __restrict__ inv_deg, float* __restrict__ ampv,
                       float* __restrict__ attv) {
    int n = blockIdx.x * 256 + threadIdx.x;
    if (n < N_NODES) {
        float avg = logsum[0] / (float)N_NODES;
        float degf = fmaxf((float)cnt[n], 1.0f);
        inv_deg[n] = 1.0f / degf;
        float ld = logf(degf + 1.0f);
        ampv[n] = ld / avg;
        attv[n] = avg / ld;
    }
}

// ---------------------------------------------------------------------------
// MFMA k_pre (3-product split, passing R10 version)
__global__ __launch_bounds__(256, 4) void k_pre(const float* __restrict__ x,
                                                const u16* __restrict__ PreS,
                                                const float* __restrict__ pre_b,
                                                float* __restrict__ p,
                                                float* __restrict__ q) {
    __shared__ u16 ldsB[2 * 8192];   // [2 ch][2 sp][8 nt][512 u16] = 32 KB
    int t = threadIdx.x;
    int w = t >> 6;
    int lane = t & 63;
    int m = lane & 15;
    int qh = lane >> 4;
    int rowBase = blockIdx.x * 64;

    int myrow = rowBase + 16 * w + m;
    bool vr = myrow < N_NODES;
    int crow = vr ? myrow : 0;
    const float* xrow = x + (size_t)crow * 64;

    int bo = m * 32 + ((qh + (m >> 1)) & 3) * 8;

    // stage H/M splits: 32 x 1KB units; unit u: ch=u>>4, sp=(u>>3)&1, nt=u&7
    for (int u = w; u < 32; u += 4) {
        int ch = u >> 4, sp = (u >> 3) & 1, nt = u & 7;
        const char* g = (const char*)PreS + (size_t)ch * 24576 + sp * 8192
                      + nt * 1024 + lane * 16;
        char* l = (char*)ldsB + u * 1024;
        gl_lds16(g, l);
    }
    // A: both 32-col chunks of this lane's row (unconditional, clamped row)
    float fa[2][8];
    #pragma unroll
    for (int ch = 0; ch < 2; ++ch) {
        const float* sp = xrow + ch * 32 + qh * 8;
        float4 u0 = *(const float4*)sp;
        float4 u1 = *(const float4*)(sp + 4);
        fa[ch][0] = vr ? u0.x : 0.f; fa[ch][1] = vr ? u0.y : 0.f;
        fa[ch][2] = vr ? u0.z : 0.f; fa[ch][3] = vr ? u0.w : 0.f;
        fa[ch][4] = vr ? u1.x : 0.f; fa[ch][5] = vr ? u1.y : 0.f;
        fa[ch][6] = vr ? u1.z : 0.f; fa[ch][7] = vr ? u1.w : 0.f;
    }
    asm volatile("s_waitcnt vmcnt(0)" ::: "memory");
    __syncthreads();

    floatx4 acc[8] = {};
    #pragma unroll
    for (int ch = 0; ch < 2; ++ch) {
        union { u32 u[4]; short8 s8; } AH, AM;
        #pragma unroll
        for (int i = 0; i < 4; ++i) {
            float f0 = fa[ch][2 * i], f1 = fa[ch][2 * i + 1];
            u32 b0 = __float_as_uint(f0), b1 = __float_as_uint(f1);
            u32 h0 = b0 & 0xFFFF0000u,  h1 = b1 & 0xFFFF0000u;
            float r0 = f0 - __uint_as_float(h0);
            float r1 = f1 - __uint_as_float(h1);
            u32 m0 = __float_as_uint(r0) & 0xFFFF0000u;
            u32 m1 = __float_as_uint(r1) & 0xFFFF0000u;
            AH.u[i] = (h0 >> 16) | h1;
            AM.u[i] = (m0 >> 16) | m1;
        }
        const u16* Bb = ldsB + ch * 8192;
        #pragma unroll
        for (int nt = 0; nt < 8; ++nt) {
            short8 bH = *(const short8*)(Bb + nt * 512 + bo);
            short8 bM = *(const short8*)(Bb + 4096 + nt * 512 + bo);
            acc[nt] = __builtin_amdgcn_mfma_f32_16x16x32_bf16(AH.s8, bH, acc[nt], 0, 0, 0);
            acc[nt] = __builtin_amdgcn_mfma_f32_16x16x32_bf16(AH.s8, bM, acc[nt], 0, 0, 0);
            acc[nt] = __builtin_amdgcn_mfma_f32_16x16x32_bf16(AM.s8, bH, acc[nt], 0, 0, 0);
        }
    }

    int col = m;
    #pragma unroll
    for (int nt = 0; nt < 8; ++nt) {
        int cbase = (nt & 3) * 16 + col;
        float bias = (nt < 4) ? pre_b[cbase] : 0.f;
        float* outp = (nt < 4) ? p : q;
        #pragma unroll
        for (int reg = 0; reg < 4; ++reg) {
            int grow = rowBase + 16 * w + qh * 4 + reg;
            if (grow < N_NODES)
                outp[(size_t)grow * 64 + cbase] = acc[nt][reg] + bias;
        }
    }
}

// ---------------------------------------------------------------------------
// Aggregation (unchanged, passing)
__global__ __launch_bounds__(256) void k_aggr(const float* __restrict__ p,
                                              const float* __restrict__ q,
                                              const int* __restrict__ row_start,
                                              const int* __restrict__ csr_src,
                                              const float* __restrict__ inv_deg,
                                              float* __restrict__ aggr) {
    int wid  = (blockIdx.x * 256 + threadIdx.x) >> 6;
    int lane = threadIdx.x & 63;
    if (wid >= N_NODES) return;
    int n = wid;
    int beg = row_start[n], end = row_start[n + 1];
    float sum = 0.f, sq = 0.f;
    float mn = INFINITY, mx = -INFINITY;
    int e = beg;
    for (; e + 7 < end; e += 8) {
        float qv[8];
        #pragma unroll
        for (int u = 0; u < 8; ++u) {
            int s = csr_src[e + u];
            qv[u] = q[(size_t)s * 64 + lane];
        }
        #pragma unroll
        for (int u = 0; u < 8; ++u) {
            float m = qv[u];
            sum += m; sq += m * m;
            mn = fminf(mn, m); mx = fmaxf(mx, m);
        }
    }
    for (; e + 3 < end; e += 4) {
        float qv[4];
        #pragma unroll
        for (int u = 0; u < 4; ++u) {
            int s = csr_src[e + u];
            qv[u] = q[(size_t)s * 64 + lane];
        }
        #pragma unroll
        for (int u = 0; u < 4; ++u) {
            float m = qv[u];
            sum += m; sq += m * m;
            mn = fminf(mn, m); mx = fmaxf(mx, m);
        }
    }
    for (; e < end; ++e) {
        int s = csr_src[e];
        float m = q[(size_t)s * 64 + lane];
        sum += m; sq += m * m;
        mn = fminf(mn, m); mx = fmaxf(mx, m);
    }
    float* a = aggr + (size_t)n * 256;
    if (end <= beg) {
        a[lane]       = 0.f;
        a[64 + lane]  = 0.f;
        a[128 + lane] = 0.f;
        a[192 + lane] = sqrtf(EPS);
    } else {
        float pv = p[n * 64 + lane];
        float id = inv_deg[n];
        float meanq = sum * id;
        float var = fmaxf(sq * id - meanq * meanq, 0.f);
        a[lane]       = pv + meanq;
        a[64 + lane]  = pv + mn;
        a[128 + lane] = pv + mx;
        a[192 + lane] = sqrtf(var + EPS);
    }
}

// ---------------------------------------------------------------------------
// MFMA k_post (R13 fused-pool version, passing): persistent-LDS N-split,
// 3-product, XCD pair swizzle. When batch != nullptr (last layer) the
// epilogue run-accumulates ReLU'd outputs into g_sum per graph instead of
// storing xout (rows monotonic per thread, batch sorted -> ~1-2 atomicAdds
// per thread). LDS: [26 ch][2 split][2 ntile][512 u16] = 106496 B.
__global__ __launch_bounds__(1024, 4) void k_post(const float* __restrict__ x,
                                                  const float* __restrict__ aggr,
                                                  const float* __restrict__ ampv,
                                                  const float* __restrict__ attv,
                                                  const u16* __restrict__ WkS,
                                                  const float* __restrict__ bc,
                                                  float* __restrict__ xout,
                                                  const int* __restrict__ batch,
                                                  float* __restrict__ g_sum) {
    extern __shared__ u16 ldsB[];
    int t = threadIdx.x;
    int w = t >> 6;                 // wave 0..15
    int lane = t & 63;
    int m = lane & 15;
    int qh = lane >> 4;

    // pair swizzle: b = s + 8*(2*q2 + nh); r = 8*q2 + s; both nh share b%8
    int b  = blockIdx.x;
    int s8 = b & 7;
    int g  = b >> 3;
    int q2 = g >> 1;
    int nh = g & 1;                 // ntile half: 0 -> cols 0..31, 1 -> 32..63
    int r  = 8 * q2 + s8;
    if (r >= 98) return;            // 98 = ceil(N_NODES/512); 12 idle blocks
    int rowBase = r * 512 + 32 * w;

    // ---- stage H/M splits of this half: 104 x 1KB units ----
    for (int u = w; u < 104; u += 16) {
        int ch = u >> 2;
        int sp = (u >> 1) & 1;
        int h2 = u & 1;
        const char* gp = (const char*)WkS + ch * 12288 + sp * 4096
                       + nh * 2048 + h2 * 1024 + lane * 16;
        char* l = (char*)ldsB + u * 1024;
        gl_lds16(gp, l);
    }

    int row0 = rowBase + m;
    int row1 = row0 + 16;
    int cr0 = (row0 < N_NODES) ? row0 : 0;
    int cr1 = (row1 < N_NODES) ? row1 : 0;
    const float* xr0 = x + (size_t)cr0 * 64;
    const float* xr1 = x + (size_t)cr1 * 64;
    const float* ar0 = aggr + (size_t)cr0 * 256;
    const float* ar1 = aggr + (size_t)cr1 * 256;

    int bo = m * 32 + ((qh + (m >> 1)) & 3) * 8;   // u16 offset in 512-block

    floatx4 accP0[2] = {}, accA0[2] = {}, accT0[2] = {};
    floatx4 accP1[2] = {}, accA1[2] = {}, accT1[2] = {};

    float f0[8], f1[8];
    union U8 { u32 u[4]; short8 s8v; };
    U8 AH0, AM0, AH1, AM1;

    auto loadRaw = [&](const float* sp, float* f) {
        float4 u0 = *(const float4*)(sp + qh * 8);
        float4 u1 = *(const float4*)(sp + qh * 8 + 4);
        f[0] = u0.x; f[1] = u0.y; f[2] = u0.z; f[3] = u0.w;
        f[4] = u1.x; f[5] = u1.y; f[6] = u1.z; f[7] = u1.w;
    };
    auto split2 = [&](const float* f, U8& H, U8& M8) {
        #pragma unroll
        for (int i = 0; i < 4; ++i) {
            float v0 = f[2 * i], v1 = f[2 * i + 1];
            u32 b0 = __float_as_uint(v0), b1 = __float_as_uint(v1);
            u32 h0 = b0 & 0xFFFF0000u,  h1 = b1 & 0xFFFF0000u;
            float r0 = v0 - __uint_as_float(h0);
            float r1 = v1 - __uint_as_float(h1);
            u32 m0 = __float_as_uint(r0) & 0xFFFF0000u;
            u32 m1 = __float_as_uint(r1) & 0xFFFF0000u;
            H.u[i]  = (h0 >> 16) | h1;
            M8.u[i] = (m0 >> 16) | m1;
        }
    };
    // one K-chunk: 4 LDS b128 reads + 12 MFMAs; 4 independent chains
    // interleaved so a dependent pair is 4 issues apart.
    #define MF(A, B, C) C = __builtin_amdgcn_mfma_f32_16x16x32_bf16((A).s8v, (B), (C), 0, 0, 0)
    auto chunkMM = [&](int ch, floatx4* A0, floatx4* A1) {
        const u16* pB = ldsB + ch * 2048 + bo;
        short8 bH0 = *(const short8*)(pB);
        short8 bH1 = *(const short8*)(pB + 512);
        short8 bM0 = *(const short8*)(pB + 1024);
        short8 bM1 = *(const short8*)(pB + 1536);
        MF(AH0, bH0, A0[0]); MF(AH1, bH0, A1[0]); MF(AH0, bH1, A0[1]); MF(AH1, bH1, A1[1]);
        MF(AH0, bM0, A0[0]); MF(AH1, bM0, A1[0]); MF(AH0, bM1, A0[1]); MF(AH1, bM1, A1[1]);
        MF(AM0, bH0, A0[0]); MF(AM1, bH0, A1[0]); MF(AM0, bH1, A0[1]); MF(AM1, bH1, A1[1]);
    };

    // A(g0) loads, then drain stage DMAs (+these loads) once, one barrier.
    loadRaw(xr0, f0); loadRaw(xr1, f1);
    asm volatile("s_waitcnt vmcnt(0)" ::: "memory");
    __syncthreads();

    // group 0: x cols 0..31 (chunk 0)
    split2(f0, AH0, AM0); split2(f1, AH1, AM1);
    loadRaw(xr0 + 32, f0); loadRaw(xr1 + 32, f1);   // prefetch group 1
    chunkMM(0, accP0, accP1);
    // group 1: x cols 32..63 (chunk 1)
    split2(f0, AH0, AM0); split2(f1, AH1, AM1);
    loadRaw(ar0, f0); loadRaw(ar1, f1);             // prefetch group 2 (aggr 0)
    chunkMM(1, accP0, accP1);
    // groups 2..9: aggr groups j=0..7, chunks 2+3j (P), +1 (A), +2 (T)
    for (int j = 0; j < 8; ++j) {
        split2(f0, AH0, AM0); split2(f1, AH1, AM1);
        if (j < 7) { loadRaw(ar0 + (j + 1) * 32, f0); loadRaw(ar1 + (j + 1) * 32, f1); }
        int ch = 2 + 3 * j;
        chunkMM(ch,     accP0, accP1);
        chunkMM(ch + 1, accA0, accA1);
        chunkMM(ch + 2, accT0, accT1);
    }
    #undef MF

    // epilogue: out = P + amp[row]*A + att[row]*T + bias, ReLU  (N-split cols)
    int col = m;
    int cb0 = (nh * 2 + 0) * 16 + col;
    int cb1 = (nh * 2 + 1) * 16 + col;
    if (batch == nullptr) {
        #pragma unroll
        for (int frag = 0; frag < 2; ++frag) {
            #pragma unroll
            for (int reg = 0; reg < 4; ++reg) {
                int grow = rowBase + 16 * frag + qh * 4 + reg;
                if (grow < N_NODES) {
                    float av = ampv[grow], tv = attv[grow];
                    #pragma unroll
                    for (int nt = 0; nt < 2; ++nt) {
                        int cbase = nt ? cb1 : cb0;
                        float pv  = frag ? accP1[nt][reg] : accP0[nt][reg];
                        float av2 = frag ? accA1[nt][reg] : accA0[nt][reg];
                        float tv2 = frag ? accT1[nt][reg] : accT0[nt][reg];
                        float v = pv + av * av2 + tv * tv2 + bc[cbase];
                        xout[(size_t)grow * 64 + cbase] = fmaxf(v, 0.f);
                    }
                }
            }
        }
    } else {
        // fused pooling (last layer): run-accumulate over this thread's 8
        // monotonic rows, one atomicAdd pair per batch-run.
        float acc0 = 0.f, acc1 = 0.f;
        int cur = -1;
        float bias0 = bc[cb0], bias1 = bc[cb1];
        #pragma unroll
        for (int frag = 0; frag < 2; ++frag) {
            #pragma unroll
            for (int reg = 0; reg < 4; ++reg) {
                int grow = rowBase + 16 * frag + qh * 4 + reg;
                if (grow < N_NODES) {
                    float av = ampv[grow], tv = attv[grow];
                    float p0 = frag ? accP1[0][reg] : accP0[0][reg];
                    float a0 = frag ? accA1[0][reg] : accA0[0][reg];
                    float t0 = frag ? accT1[0][reg] : accT0[0][reg];
                    float p1 = frag ? accP1[1][reg] : accP0[1][reg];
                    float a1 = frag ? accA1[1][reg] : accA0[1][reg];
                    float t1 = frag ? accT1[1][reg] : accT0[1][reg];
                    float v0 = fmaxf(p0 + av * a0 + tv * t0 + bias0, 0.f);
                    float v1 = fmaxf(p1 + av * a1 + tv * t1 + bias1, 0.f);
                    int bb = batch[grow];
                    if (bb != cur) {
                        if (cur >= 0) {
                            atomicAdd(&g_sum[cur * 64 + cb0], acc0);
                            atomicAdd(&g_sum[cur * 64 + cb1], acc1);
                        }
                        cur = bb; acc0 = 0.f; acc1 = 0.f;
                    }
                    acc0 += v0; acc1 += v1;
                }
            }
        }
        if (cur >= 0) {
            atomicAdd(&g_sum[cur * 64 + cb0], acc0);
            atomicAdd(&g_sum[cur * 64 + cb1], acc1);
        }
    }
}

// ---------------------------------------------------------------------------
__global__ __launch_bounds__(256) void k_mlp(const float* __restrict__ g_sum,
                                             const int* __restrict__ g_cnt,
                                             const float* __restrict__ w1,
                                             const float* __restrict__ b1,
                                             const float* __restrict__ w2,
                                             const float* __restrict__ b2,
                                             float* __restrict__ out) {
    __shared__ float g[64][64];
    __shared__ float h[64][64];
    __shared__ float wT[64][65];
    int t = threadIdx.x;
    for (int idx = t; idx < 4096; idx += 256) {
        int gi = idx >> 6, c = idx & 63;
        float cntf = fmaxf((float)g_cnt[gi], 1.f);
        g[gi][c] = g_sum[idx] / cntf;
    }
    for (int idx = t; idx < 4096; idx += 256) {
        int c = idx >> 6, k = idx & 63;
        wT[k][c] = w1[c * 64 + k];
    }
    __syncthreads();
    for (int idx = t; idx < 4096; idx += 256) {
        int gi = idx >> 6, c = idx & 63;
        float acc = b1[c];
        for (int k = 0; k < 64; ++k) acc += g[gi][k] * wT[k][c];
        h[gi][c] = fmaxf(acc, 0.f);
    }
    __syncthreads();
    for (int idx = t; idx < 64 * NCLASSES; idx += 256) {
        int gi = idx >> 4, c = idx & 15;
        float acc = b2[c];
        for (int k = 0; k < 64; ++k) acc += h[gi][k] * w2[c * 64 + k];
        out[gi * NCLASSES + c] = acc;
    }
}

// ---------------------------------------------------------------------------
extern "C" void kernel_launch(void* const* d_in, const int* in_sizes, int n_in,
                              void* d_out, int out_size, void* d_ws, size_t ws_size,
                              hipStream_t stream) {
    const float* x      = (const float*)d_in[0];
    const int*   ei     = (const int*)d_in[1];
    const int*   batch  = (const int*)d_in[2];
    const float* pre_w  = (const float*)d_in[3];
    const float* pre_b  = (const float*)d_in[4];
    const float* post_w = (const float*)d_in[5];
    const float* post_b = (const float*)d_in[6];
    const float* lin_w  = (const float*)d_in[7];
    const float* lin_b  = (const float*)d_in[8];
    const float* mlp_w1 = (const float*)d_in[9];
    const float* mlp_b1 = (const float*)d_in[10];
    const float* mlp_w2 = (const float*)d_in[11];
    const float* mlp_b2 = (const float*)d_in[12];

    const int* src = ei;
    const int* dst = ei + N_EDGES;

    char* base = (char*)d_ws;
    size_t off = 0;
    auto alloc = [&](size_t bytes) -> void* {
        void* ptr = base + off;
        off += (bytes + 255) & ~(size_t)255;
        return ptr;
    };
    int*   cnt       = (int*)alloc(N_NODES * 4);
    int*   row_start = (int*)alloc((N_NODES + 1) * 4);
    int*   rank      = (int*)alloc(N_EDGES * 4);
    int*   csr_src   = (int*)alloc(N_EDGES * 4);
    int*   bsum      = (int*)alloc(64 * 4);
    int*   boff      = (int*)alloc(64 * 4);
    float* logsum    = (float*)alloc(16);
    float* inv_deg   = (float*)alloc(N_NODES * 4);
    float* ampv      = (float*)alloc(N_NODES * 4);
    float* attv      = (float*)alloc(N_NODES * 4);
    float* p         = (float*)alloc((size_t)N_NODES * 64 * 4);
    float* q         = (float*)alloc((size_t)N_NODES * 64 * 4);
    float* aggr      = (float*)alloc((size_t)N_NODES * 256 * 4);
    float* xb0       = (float*)alloc((size_t)N_NODES * 64 * 4);
    float* xb1       = (float*)alloc((size_t)N_NODES * 64 * 4);
    float* g_sum     = (float*)alloc(64 * 64 * 4);
    int*   g_cnt     = (int*)alloc(64 * 4);
    u16*   WkS       = (u16*)alloc((size_t)3 * WKS_LAYER * 2);
    u16*   PreS      = (u16*)alloc((size_t)3 * PRES_LAYER * 2);
    float* bcv       = (float*)alloc(3 * 64 * 4);

    // weight folding + pre_w split + workspace/accumulator zero-init
    k_comb<<<721, 256, 0, stream>>>(post_w, lin_w, pre_w, post_b, lin_b,
                                    WkS, PreS, bcv, cnt, logsum, g_sum, g_cnt);

    k_count<<<(N_EDGES + 255) / 256, 256, 0, stream>>>(dst, cnt, rank);
    k_chunk_sums<<<NCHUNKS, 256, 0, stream>>>(cnt, bsum, logsum);
    k_scan_top<<<1, 64, 0, stream>>>(bsum, boff, row_start);
    k_scan_chunks<<<NCHUNKS, 256, 0, stream>>>(cnt, boff, batch, row_start,
                                               g_cnt);
    k_scatter<<<(N_EDGES + 255) / 256, 256, 0, stream>>>(src, dst, rank,
                                                         row_start, csr_src);
    k_scal<<<(N_NODES + 255) / 256, 256, 0, stream>>>(cnt, logsum, inv_deg,
                                                      ampv, attv);

    const int PRE_BLOCKS  = (N_NODES + 63) / 64;   // 782
    const int POST_BLOCKS = 208;                    // 2 N-halves x 98 + 12 idle
    const float* xin = x;
    float* bufs[3] = {xb0, xb1, xb0};
    for (int l = 0; l < NLAYERS; ++l) {
        k_pre<<<PRE_BLOCKS, 256, 0, stream>>>(xin, PreS + (size_t)l * PRES_LAYER,
                                              pre_b + l * 64, p, q);
        k_aggr<<<(N_NODES + 3) / 4, 256, 0, stream>>>(p, q, row_start, csr_src,
                                                      inv_deg, aggr);
        float* xo = bufs[l];
        const int* bptr = (l == NLAYERS - 1) ? batch : nullptr;
        k_post<<<POST_BLOCKS, 1024, KPOST_LDS_BYTES, stream>>>(
            xin, aggr, ampv, attv, WkS + (size_t)l * WKS_LAYER,
            bcv + l * 64, xo, bptr, g_sum);
        xin = xo;
    }

    k_mlp<<<1, 256, 0, stream>>>(g_sum, g_cnt, mlp_w1, mlp_b1, mlp_w2, mlp_b2,
                                 (float*)d_out);
}

// Round 15
// 396.411 us; speedup vs baseline: 1.1482x; 1.1462x over previous
//
#include <hip/hip_runtime.h>
#include <math.h>

#define N_NODES   50000
#define N_EDGES   800000
#define NUM_GRAPHS 64
#define FDIM      64
#define HDIM      64
#define NLAYERS   3
#define NCLASSES  16
#define EPS       1e-5f

#define SCAN_CHUNK 1024
#define NCHUNKS ((N_NODES + SCAN_CHUNK - 1) / SCAN_CHUNK)   // 49

typedef unsigned short u16;
typedef unsigned int   u32;
typedef __attribute__((ext_vector_type(8))) short short8;   // 8 bf16 (4 VGPRs)
typedef __attribute__((ext_vector_type(4))) float floatx4;  // MFMA accum

// WkS layout per layer (u16 bf16 bits):
//   [26 kchunk][3 split][4 ntile][16 n][32 k-swizzled] -> 159744 u16 per layer
// K-order: chunks 0-1 = x cols 0..63; then for aggr group j (j=0..7, 32 cols):
//   chunk 2+3j+0 = plain, +1 = amp, +2 = att.
// k position within a chunk row is swizzled: element (n16, kin=qh*8+jj) stored
// at n16*32 + ((qh + (n16>>1)) & 3)*8 + jj  (2-way LDS bank spread on read).
// The L split is written by k_comb but not consumed (3-product scheme).
#define WKS_LAYER 159744
// PreS layout per layer: [2 kchunk][3 split][8 ntile][16 n][32 k-swizzled]
#define PRES_LAYER 24576
// k_post dynamic LDS: H/M splits of one ntile-HALF, fully resident:
//   [26 ch][2 split][2 ntile][512 u16] = 53248 u16 = 104 KB
#define KPOST_LDS_BYTES 106496

// ---------------------------------------------------------------------------
__device__ inline void split1(float f, u16& h, u16& m, u16& l) {
    u32 b  = __float_as_uint(f);
    u32 hb = b & 0xFFFF0000u;
    float r = f - __uint_as_float(hb);
    u32 mb = __float_as_uint(r) & 0xFFFF0000u;
    float r2 = r - __uint_as_float(mb);
    u32 lb = __float_as_uint(r2) & 0xFFFF0000u;
    h = (u16)(hb >> 16); m = (u16)(mb >> 16); l = (u16)(lb >> 16);
}

// async global->LDS DMA, 16B per lane (dest = wave-uniform base + lane*16)
__device__ inline void gl_lds16(const void* g, void* l) {
    __builtin_amdgcn_global_load_lds(
        (const __attribute__((address_space(1))) u32*)g,
        (__attribute__((address_space(3))) u32*)l, 16, 0, 0);
}

// ---------------------------------------------------------------------------
// Weight folding Wk = (lin_w @ post_w) -> 3-way bf16 split (K-permuted,
// swizzled); PreS = pre_w 3-way bf16 split; bc = lin_b + lin_w@post_b.
// Zero-inits cnt/logsum AND g_sum (first kernel -> precedes the layer-3
// k_post fused-pool accumulation).
__global__ __launch_bounds__(256) void k_comb(const float* __restrict__ post_w,
                                              const float* __restrict__ lin_w,
                                              const float* __restrict__ pre_w,
                                              const float* __restrict__ post_b,
                                              const float* __restrict__ lin_b,
                                              u16* __restrict__ WkS,
                                              u16* __restrict__ PreS,
                                              float* __restrict__ bcv,
                                              int* __restrict__ cnt,
                                              float* __restrict__ logsum,
                                              float* __restrict__ g_sum) {
    int b = blockIdx.x, t = threadIdx.x;
    int zi = b * 256 + t;
    if (zi < N_NODES) cnt[zi] = 0;
    if (zi == 0) *logsum = 0.f;
    if (zi < 4096) g_sum[zi] = 0.f;

    if (b < 624) {
        int c  = t & 63;
        int kl = t >> 6;
        int l  = b / 208;
        int o  = (b % 208) * 4 + kl;          // original K column in [0,832)
        const float* lw = lin_w + (size_t)l * 4096 + c * 64;
        const float* pw = post_w + (size_t)l * 53248 + o;
        float acc = 0.f;
        #pragma unroll 8
        for (int j = 0; j < 64; ++j)
            acc += lw[j] * pw[(size_t)j * 832];
        u16 h, m, lo;
        split1(acc, h, m, lo);

        int kn;
        if (o < 64) kn = o;
        else {
            int s  = (o - 64) >> 8;           // 0 plain, 1 amp, 2 att
            int mm = (o - 64) & 255;
            int j  = mm >> 5, r = mm & 31;
            kn = 64 + j * 96 + s * 32 + r;
        }
        int ch  = kn >> 5;
        int kin = kn & 31;
        int n16 = c & 15, nt = c >> 4;
        int swk = (((kin >> 3) + (n16 >> 1)) & 3) * 8 + (kin & 7);
        size_t base = (size_t)l * WKS_LAYER + (size_t)ch * 6144
                    + nt * 512 + n16 * 32 + swk;
        WkS[base]        = h;
        WkS[base + 2048] = m;
        WkS[base + 4096] = lo;
    } else if (b == 624) {
        if (t < 192) {
            int l = t >> 6, c = t & 63;
            float acc = lin_b[l * 64 + c];
            for (int j = 0; j < 64; ++j)
                acc += lin_w[(size_t)l * 4096 + c * 64 + j] * post_b[l * 64 + j];
            bcv[l * 64 + c] = acc;
        }
    } else {
        int i = (b - 625) * 256 + t;
        int l = i >> 13;
        int rem = i & 8191;
        int c128 = rem >> 6;
        int k = rem & 63;
        float v;
        if (c128 < 64) v = pre_w[(size_t)l * 8192 + c128 * 128 + k];
        else           v = pre_w[(size_t)l * 8192 + (c128 - 64) * 128 + 64 + k];
        u16 h, m, lo;
        split1(v, h, m, lo);
        int ch = k >> 5, kin = k & 31;
        int nt = c128 >> 4, n16 = c128 & 15;
        int swk = (((kin >> 3) + (n16 >> 1)) & 3) * 8 + (kin & 7);
        size_t base = (size_t)l * PRES_LAYER + (size_t)ch * 12288
                    + nt * 512 + n16 * 32 + swk;
        PreS[base]        = h;
        PreS[base + 4096] = m;
        PreS[base + 8192] = lo;
    }
}

// ---------------------------------------------------------------------------
__global__ void k_count(const int* __restrict__ dst, int* __restrict__ cnt,
                        int* __restrict__ rank) {
    int e = blockIdx.x * 256 + threadIdx.x;
    if (e < N_EDGES) rank[e] = atomicAdd(&cnt[dst[e]], 1);
}

__global__ void k_chunk_sums(const int* __restrict__ cnt, int* __restrict__ bsum,
                             float* __restrict__ logsum) {
    __shared__ int   ired[256];
    __shared__ float lred[256];
    int b = blockIdx.x, t = threadIdx.x;
    int base = b * SCAN_CHUNK;
    int s = 0; float ls = 0.f;
    for (int i = t; i < SCAN_CHUNK; i += 256) {
        int idx = base + i;
        if (idx < N_NODES) {
            int v = cnt[idx];
            s += v;
            ls += logf((float)v + 1.0f);
        }
    }
    ired[t] = s; lred[t] = ls;
    __syncthreads();
    for (int off = 128; off > 0; off >>= 1) {
        if (t < off) { ired[t] += ired[t + off]; lred[t] += lred[t + off]; }
        __syncthreads();
    }
    if (t == 0) { bsum[b] = ired[0]; atomicAdd(logsum, lred[0]); }
}

__global__ void k_scan_top(const int* __restrict__ bsum, int* __restrict__ boff,
                           int* __restrict__ row_start) {
    if (threadIdx.x == 0) {
        int acc = 0;
        for (int i = 0; i < NCHUNKS; ++i) { boff[i] = acc; acc += bsum[i]; }
        row_start[N_NODES] = acc;
    }
}

// pristine R12 chunk scan (no batch counting -- R14's contended atomics
// cost 55 us; per-graph counts now come from binary search in k_mlp)
__global__ void k_scan_chunks(const int* __restrict__ cnt, const int* __restrict__ boff,
                              int* __restrict__ row_start) {
    __shared__ int tsum[256];
    int b = blockIdx.x, t = threadIdx.x;
    int base = b * SCAN_CHUNK + t * 4;
    int v[4]; int s = 0;
    #pragma unroll
    for (int i = 0; i < 4; ++i) {
        int idx = base + i;
        v[i] = (idx < N_NODES) ? cnt[idx] : 0;
        s += v[i];
    }
    tsum[t] = s;
    __syncthreads();
    for (int off = 1; off < 256; off <<= 1) {
        int val = (t >= off) ? tsum[t - off] : 0;
        __syncthreads();
        tsum[t] += val;
        __syncthreads();
    }
    int excl = boff[b] + tsum[t] - s;
    #pragma unroll
    for (int i = 0; i < 4; ++i) {
        int idx = base + i;
        if (idx < N_NODES) row_start[idx] = excl;
        excl += v[i];
    }
}

// atomic-free scatter: slot = row_start[dst] + rank (plain writes, L2-coalesced)
__global__ void k_scatter(const int* __restrict__ src, const int* __restrict__ dst,
                          const int* __restrict__ rank,
                          const int* __restrict__ row_start,
                          int* __restrict__ csr_src) {
    int e = blockIdx.x * 256 + threadIdx.x;
    if (e < N_EDGES) {
        int d = dst[e];
        csr_src[row_start[d] + rank[e]] = src[e];
    }
}

// per-node degree scalers (zeroing moved to k_comb)
__global__ void k_scal(const int* __restrict__ cnt, const float* __restrict__ logsum,
                       float* __restrict__ inv_deg, float* __restrict__ ampv,
                       float* __restrict__ attv) {
    int n = blockIdx.x * 256 + threadIdx.x;
    if (n < N_NODES) {
        float avg = logsum[0] / (float)N_NODES;
        float degf = fmaxf((float)cnt[n], 1.0f);
        inv_deg[n] = 1.0f / degf;
        float ld = logf(degf + 1.0f);
        ampv[n] = ld / avg;
        attv[n] = avg / ld;
    }
}

// ---------------------------------------------------------------------------
// MFMA k_pre (3-product split, passing R10 version)
__global__ __launch_bounds__(256, 4) void k_pre(const float* __restrict__ x,
                                                const u16* __restrict__ PreS,
                                                const float* __restrict__ pre_b,
                                                float* __restrict__ p,
                                                float* __restrict__ q) {
    __shared__ u16 ldsB[2 * 8192];   // [2 ch][2 sp][8 nt][512 u16] = 32 KB
    int t = threadIdx.x;
    int w = t >> 6;
    int lane = t & 63;
    int m = lane & 15;
    int qh = lane >> 4;
    int rowBase = blockIdx.x * 64;

    int myrow = rowBase + 16 * w + m;
    bool vr = myrow < N_NODES;
    int crow = vr ? myrow : 0;
    const float* xrow = x + (size_t)crow * 64;

    int bo = m * 32 + ((qh + (m >> 1)) & 3) * 8;

    // stage H/M splits: 32 x 1KB units; unit u: ch=u>>4, sp=(u>>3)&1, nt=u&7
    for (int u = w; u < 32; u += 4) {
        int ch = u >> 4, sp = (u >> 3) & 1, nt = u & 7;
        const char* g = (const char*)PreS + (size_t)ch * 24576 + sp * 8192
                      + nt * 1024 + lane * 16;
        char* l = (char*)ldsB + u * 1024;
        gl_lds16(g, l);
    }
    // A: both 32-col chunks of this lane's row (unconditional, clamped row)
    float fa[2][8];
    #pragma unroll
    for (int ch = 0; ch < 2; ++ch) {
        const float* sp = xrow + ch * 32 + qh * 8;
        float4 u0 = *(const float4*)sp;
        float4 u1 = *(const float4*)(sp + 4);
        fa[ch][0] = vr ? u0.x : 0.f; fa[ch][1] = vr ? u0.y : 0.f;
        fa[ch][2] = vr ? u0.z : 0.f; fa[ch][3] = vr ? u0.w : 0.f;
        fa[ch][4] = vr ? u1.x : 0.f; fa[ch][5] = vr ? u1.y : 0.f;
        fa[ch][6] = vr ? u1.z : 0.f; fa[ch][7] = vr ? u1.w : 0.f;
    }
    asm volatile("s_waitcnt vmcnt(0)" ::: "memory");
    __syncthreads();

    floatx4 acc[8] = {};
    #pragma unroll
    for (int ch = 0; ch < 2; ++ch) {
        union { u32 u[4]; short8 s8; } AH, AM;
        #pragma unroll
        for (int i = 0; i < 4; ++i) {
            float f0 = fa[ch][2 * i], f1 = fa[ch][2 * i + 1];
            u32 b0 = __float_as_uint(f0), b1 = __float_as_uint(f1);
            u32 h0 = b0 & 0xFFFF0000u,  h1 = b1 & 0xFFFF0000u;
            float r0 = f0 - __uint_as_float(h0);
            float r1 = f1 - __uint_as_float(h1);
            u32 m0 = __float_as_uint(r0) & 0xFFFF0000u;
            u32 m1 = __float_as_uint(r1) & 0xFFFF0000u;
            AH.u[i] = (h0 >> 16) | h1;
            AM.u[i] = (m0 >> 16) | m1;
        }
        const u16* Bb = ldsB + ch * 8192;
        #pragma unroll
        for (int nt = 0; nt < 8; ++nt) {
            short8 bH = *(const short8*)(Bb + nt * 512 + bo);
            short8 bM = *(const short8*)(Bb + 4096 + nt * 512 + bo);
            acc[nt] = __builtin_amdgcn_mfma_f32_16x16x32_bf16(AH.s8, bH, acc[nt], 0, 0, 0);
            acc[nt] = __builtin_amdgcn_mfma_f32_16x16x32_bf16(AH.s8, bM, acc[nt], 0, 0, 0);
            acc[nt] = __builtin_amdgcn_mfma_f32_16x16x32_bf16(AM.s8, bH, acc[nt], 0, 0, 0);
        }
    }

    int col = m;
    #pragma unroll
    for (int nt = 0; nt < 8; ++nt) {
        int cbase = (nt & 3) * 16 + col;
        float bias = (nt < 4) ? pre_b[cbase] : 0.f;
        float* outp = (nt < 4) ? p : q;
        #pragma unroll
        for (int reg = 0; reg < 4; ++reg) {
            int grow = rowBase + 16 * w + qh * 4 + reg;
            if (grow < N_NODES)
                outp[(size_t)grow * 64 + cbase] = acc[nt][reg] + bias;
        }
    }
}

// ---------------------------------------------------------------------------
// Aggregation (unchanged, passing)
__global__ __launch_bounds__(256) void k_aggr(const float* __restrict__ p,
                                              const float* __restrict__ q,
                                              const int* __restrict__ row_start,
                                              const int* __restrict__ csr_src,
                                              const float* __restrict__ inv_deg,
                                              float* __restrict__ aggr) {
    int wid  = (blockIdx.x * 256 + threadIdx.x) >> 6;
    int lane = threadIdx.x & 63;
    if (wid >= N_NODES) return;
    int n = wid;
    int beg = row_start[n], end = row_start[n + 1];
    float sum = 0.f, sq = 0.f;
    float mn = INFINITY, mx = -INFINITY;
    int e = beg;
    for (; e + 7 < end; e += 8) {
        float qv[8];
        #pragma unroll
        for (int u = 0; u < 8; ++u) {
            int s = csr_src[e + u];
            qv[u] = q[(size_t)s * 64 + lane];
        }
        #pragma unroll
        for (int u = 0; u < 8; ++u) {
            float m = qv[u];
            sum += m; sq += m * m;
            mn = fminf(mn, m); mx = fmaxf(mx, m);
        }
    }
    for (; e + 3 < end; e += 4) {
        float qv[4];
        #pragma unroll
        for (int u = 0; u < 4; ++u) {
            int s = csr_src[e + u];
            qv[u] = q[(size_t)s * 64 + lane];
        }
        #pragma unroll
        for (int u = 0; u < 4; ++u) {
            float m = qv[u];
            sum += m; sq += m * m;
            mn = fminf(mn, m); mx = fmaxf(mx, m);
        }
    }
    for (; e < end; ++e) {
        int s = csr_src[e];
        float m = q[(size_t)s * 64 + lane];
        sum += m; sq += m * m;
        mn = fminf(mn, m); mx = fmaxf(mx, m);
    }
    float* a = aggr + (size_t)n * 256;
    if (end <= beg) {
        a[lane]       = 0.f;
        a[64 + lane]  = 0.f;
        a[128 + lane] = 0.f;
        a[192 + lane] = sqrtf(EPS);
    } else {
        float pv = p[n * 64 + lane];
        float id = inv_deg[n];
        float meanq = sum * id;
        float var = fmaxf(sq * id - meanq * meanq, 0.f);
        a[lane]       = pv + meanq;
        a[64 + lane]  = pv + mn;
        a[128 + lane] = pv + mx;
        a[192 + lane] = sqrtf(var + EPS);
    }
}

// ---------------------------------------------------------------------------
// MFMA k_post (R13 fused-pool version, passing): persistent-LDS N-split,
// 3-product, XCD pair swizzle. When batch != nullptr (last layer) the
// epilogue run-accumulates ReLU'd outputs into g_sum per graph instead of
// storing xout (rows monotonic per thread, batch sorted -> ~1-2 atomicAdds
// per thread). LDS: [26 ch][2 split][2 ntile][512 u16] = 106496 B.
__global__ __launch_bounds__(1024, 4) void k_post(const float* __restrict__ x,
                                                  const float* __restrict__ aggr,
                                                  const float* __restrict__ ampv,
                                                  const float* __restrict__ attv,
                                                  const u16* __restrict__ WkS,
                                                  const float* __restrict__ bc,
                                                  float* __restrict__ xout,
                                                  const int* __restrict__ batch,
                                                  float* __restrict__ g_sum) {
    extern __shared__ u16 ldsB[];
    int t = threadIdx.x;
    int w = t >> 6;                 // wave 0..15
    int lane = t & 63;
    int m = lane & 15;
    int qh = lane >> 4;

    // pair swizzle: b = s + 8*(2*q2 + nh); r = 8*q2 + s; both nh share b%8
    int b  = blockIdx.x;
    int s8 = b & 7;
    int g  = b >> 3;
    int q2 = g >> 1;
    int nh = g & 1;                 // ntile half: 0 -> cols 0..31, 1 -> 32..63
    int r  = 8 * q2 + s8;
    if (r >= 98) return;            // 98 = ceil(N_NODES/512); 12 idle blocks
    int rowBase = r * 512 + 32 * w;

    // ---- stage H/M splits of this half: 104 x 1KB units ----
    for (int u = w; u < 104; u += 16) {
        int ch = u >> 2;
        int sp = (u >> 1) & 1;
        int h2 = u & 1;
        const char* gp = (const char*)WkS + ch * 12288 + sp * 4096
                       + nh * 2048 + h2 * 1024 + lane * 16;
        char* l = (char*)ldsB + u * 1024;
        gl_lds16(gp, l);
    }

    int row0 = rowBase + m;
    int row1 = row0 + 16;
    int cr0 = (row0 < N_NODES) ? row0 : 0;
    int cr1 = (row1 < N_NODES) ? row1 : 0;
    const float* xr0 = x + (size_t)cr0 * 64;
    const float* xr1 = x + (size_t)cr1 * 64;
    const float* ar0 = aggr + (size_t)cr0 * 256;
    const float* ar1 = aggr + (size_t)cr1 * 256;

    int bo = m * 32 + ((qh + (m >> 1)) & 3) * 8;   // u16 offset in 512-block

    floatx4 accP0[2] = {}, accA0[2] = {}, accT0[2] = {};
    floatx4 accP1[2] = {}, accA1[2] = {}, accT1[2] = {};

    float f0[8], f1[8];
    union U8 { u32 u[4]; short8 s8v; };
    U8 AH0, AM0, AH1, AM1;

    auto loadRaw = [&](const float* sp, float* f) {
        float4 u0 = *(const float4*)(sp + qh * 8);
        float4 u1 = *(const float4*)(sp + qh * 8 + 4);
        f[0] = u0.x; f[1] = u0.y; f[2] = u0.z; f[3] = u0.w;
        f[4] = u1.x; f[5] = u1.y; f[6] = u1.z; f[7] = u1.w;
    };
    auto split2 = [&](const float* f, U8& H, U8& M8) {
        #pragma unroll
        for (int i = 0; i < 4; ++i) {
            float v0 = f[2 * i], v1 = f[2 * i + 1];
            u32 b0 = __float_as_uint(v0), b1 = __float_as_uint(v1);
            u32 h0 = b0 & 0xFFFF0000u,  h1 = b1 & 0xFFFF0000u;
            float r0 = v0 - __uint_as_float(h0);
            float r1 = v1 - __uint_as_float(h1);
            u32 m0 = __float_as_uint(r0) & 0xFFFF0000u;
            u32 m1 = __float_as_uint(r1) & 0xFFFF0000u;
            H.u[i]  = (h0 >> 16) | h1;
            M8.u[i] = (m0 >> 16) | m1;
        }
    };
    // one K-chunk: 4 LDS b128 reads + 12 MFMAs; 4 independent chains
    // interleaved so a dependent pair is 4 issues apart.
    #define MF(A, B, C) C = __builtin_amdgcn_mfma_f32_16x16x32_bf16((A).s8v, (B), (C), 0, 0, 0)
    auto chunkMM = [&](int ch, floatx4* A0, floatx4* A1) {
        const u16* pB = ldsB + ch * 2048 + bo;
        short8 bH0 = *(const short8*)(pB);
        short8 bH1 = *(const short8*)(pB + 512);
        short8 bM0 = *(const short8*)(pB + 1024);
        short8 bM1 = *(const short8*)(pB + 1536);
        MF(AH0, bH0, A0[0]); MF(AH1, bH0, A1[0]); MF(AH0, bH1, A0[1]); MF(AH1, bH1, A1[1]);
        MF(AH0, bM0, A0[0]); MF(AH1, bM0, A1[0]); MF(AH0, bM1, A0[1]); MF(AH1, bM1, A1[1]);
        MF(AM0, bH0, A0[0]); MF(AM1, bH0, A1[0]); MF(AM0, bH1, A0[1]); MF(AM1, bH1, A1[1]);
    };

    // A(g0) loads, then drain stage DMAs (+these loads) once, one barrier.
    loadRaw(xr0, f0); loadRaw(xr1, f1);
    asm volatile("s_waitcnt vmcnt(0)" ::: "memory");
    __syncthreads();

    // group 0: x cols 0..31 (chunk 0)
    split2(f0, AH0, AM0); split2(f1, AH1, AM1);
    loadRaw(xr0 + 32, f0); loadRaw(xr1 + 32, f1);   // prefetch group 1
    chunkMM(0, accP0, accP1);
    // group 1: x cols 32..63 (chunk 1)
    split2(f0, AH0, AM0); split2(f1, AH1, AM1);
    loadRaw(ar0, f0); loadRaw(ar1, f1);             // prefetch group 2 (aggr 0)
    chunkMM(1, accP0, accP1);
    // groups 2..9: aggr groups j=0..7, chunks 2+3j (P), +1 (A), +2 (T)
    for (int j = 0; j < 8; ++j) {
        split2(f0, AH0, AM0); split2(f1, AH1, AM1);
        if (j < 7) { loadRaw(ar0 + (j + 1) * 32, f0); loadRaw(ar1 + (j + 1) * 32, f1); }
        int ch = 2 + 3 * j;
        chunkMM(ch,     accP0, accP1);
        chunkMM(ch + 1, accA0, accA1);
        chunkMM(ch + 2, accT0, accT1);
    }
    #undef MF

    // epilogue: out = P + amp[row]*A + att[row]*T + bias, ReLU  (N-split cols)
    int col = m;
    int cb0 = (nh * 2 + 0) * 16 + col;
    int cb1 = (nh * 2 + 1) * 16 + col;
    if (batch == nullptr) {
        #pragma unroll
        for (int frag = 0; frag < 2; ++frag) {
            #pragma unroll
            for (int reg = 0; reg < 4; ++reg) {
                int grow = rowBase + 16 * frag + qh * 4 + reg;
                if (grow < N_NODES) {
                    float av = ampv[grow], tv = attv[grow];
                    #pragma unroll
                    for (int nt = 0; nt < 2; ++nt) {
                        int cbase = nt ? cb1 : cb0;
                        float pv  = frag ? accP1[nt][reg] : accP0[nt][reg];
                        float av2 = frag ? accA1[nt][reg] : accA0[nt][reg];
                        float tv2 = frag ? accT1[nt][reg] : accT0[nt][reg];
                        float v = pv + av * av2 + tv * tv2 + bc[cbase];
                        xout[(size_t)grow * 64 + cbase] = fmaxf(v, 0.f);
                    }
                }
            }
        }
    } else {
        // fused pooling (last layer): run-accumulate over this thread's 8
        // monotonic rows, one atomicAdd pair per batch-run.
        float acc0 = 0.f, acc1 = 0.f;
        int cur = -1;
        float bias0 = bc[cb0], bias1 = bc[cb1];
        #pragma unroll
        for (int frag = 0; frag < 2; ++frag) {
            #pragma unroll
            for (int reg = 0; reg < 4; ++reg) {
                int grow = rowBase + 16 * frag + qh * 4 + reg;
                if (grow < N_NODES) {
                    float av = ampv[grow], tv = attv[grow];
                    float p0 = frag ? accP1[0][reg] : accP0[0][reg];
                    float a0 = frag ? accA1[0][reg] : accA0[0][reg];
                    float t0 = frag ? accT1[0][reg] : accT0[0][reg];
                    float p1 = frag ? accP1[1][reg] : accP0[1][reg];
                    float a1 = frag ? accA1[1][reg] : accA0[1][reg];
                    float t1 = frag ? accT1[1][reg] : accT0[1][reg];
                    float v0 = fmaxf(p0 + av * a0 + tv * t0 + bias0, 0.f);
                    float v1 = fmaxf(p1 + av * a1 + tv * t1 + bias1, 0.f);
                    int bb = batch[grow];
                    if (bb != cur) {
                        if (cur >= 0) {
                            atomicAdd(&g_sum[cur * 64 + cb0], acc0);
                            atomicAdd(&g_sum[cur * 64 + cb1], acc1);
                        }
                        cur = bb; acc0 = 0.f; acc1 = 0.f;
                    }
                    acc0 += v0; acc1 += v1;
                }
            }
        }
        if (cur >= 0) {
            atomicAdd(&g_sum[cur * 64 + cb0], acc0);
            atomicAdd(&g_sum[cur * 64 + cb1], acc1);
        }
    }
}

// ---------------------------------------------------------------------------
// k_mlp (R15): per-graph counts via binary search on the SORTED batch array
// (64 threads x 2 searches x 16 steps -- contention-free, no extra kernel).
__global__ __launch_bounds__(256) void k_mlp(const float* __restrict__ g_sum,
                                             const int* __restrict__ batch,
                                             const float* __restrict__ w1,
                                             const float* __restrict__ b1,
                                             const float* __restrict__ w2,
                                             const float* __restrict__ b2,
                                             float* __restrict__ out) {
    __shared__ float g[64][64];
    __shared__ float h[64][64];
    __shared__ float wT[64][65];
    __shared__ float cntf[64];
    int t = threadIdx.x;
    if (t < 64) {
        // lower_bound(t) and lower_bound(t+1) on sorted batch
        int lo = 0, hi = N_NODES;
        while (lo < hi) { int mid = (lo + hi) >> 1;
                          if (batch[mid] < t) lo = mid + 1; else hi = mid; }
        int lb = lo;
        lo = 0; hi = N_NODES;
        while (lo < hi) { int mid = (lo + hi) >> 1;
                          if (batch[mid] < t + 1) lo = mid + 1; else hi = mid; }
        cntf[t] = fmaxf((float)(lo - lb), 1.f);
    }
    __syncthreads();
    for (int idx = t; idx < 4096; idx += 256) {
        int gi = idx >> 6, c = idx & 63;
        g[gi][c] = g_sum[idx] / cntf[gi];
    }
    for (int idx = t; idx < 4096; idx += 256) {
        int c = idx >> 6, k = idx & 63;
        wT[k][c] = w1[c * 64 + k];
    }
    __syncthreads();
    for (int idx = t; idx < 4096; idx += 256) {
        int gi = idx >> 6, c = idx & 63;
        float acc = b1[c];
        for (int k = 0; k < 64; ++k) acc += g[gi][k] * wT[k][c];
        h[gi][c] = fmaxf(acc, 0.f);
    }
    __syncthreads();
    for (int idx = t; idx < 64 * NCLASSES; idx += 256) {
        int gi = idx >> 4, c = idx & 15;
        float acc = b2[c];
        for (int k = 0; k < 64; ++k) acc += h[gi][k] * w2[c * 64 + k];
        out[gi * NCLASSES + c] = acc;
    }
}

// ---------------------------------------------------------------------------
extern "C" void kernel_launch(void* const* d_in, const int* in_sizes, int n_in,
                              void* d_out, int out_size, void* d_ws, size_t ws_size,
                              hipStream_t stream) {
    const float* x      = (const float*)d_in[0];
    const int*   ei     = (const int*)d_in[1];
    const int*   batch  = (const int*)d_in[2];
    const float* pre_w  = (const float*)d_in[3];
    const float* pre_b  = (const float*)d_in[4];
    const float* post_w = (const float*)d_in[5];
    const float* post_b = (const float*)d_in[6];
    const float* lin_w  = (const float*)d_in[7];
    const float* lin_b  = (const float*)d_in[8];
    const float* mlp_w1 = (const float*)d_in[9];
    const float* mlp_b1 = (const float*)d_in[10];
    const float* mlp_w2 = (const float*)d_in[11];
    const float* mlp_b2 = (const float*)d_in[12];

    const int* src = ei;
    const int* dst = ei + N_EDGES;

    char* base = (char*)d_ws;
    size_t off = 0;
    auto alloc = [&](size_t bytes) -> void* {
        void* ptr = base + off;
        off += (bytes + 255) & ~(size_t)255;
        return ptr;
    };
    int*   cnt       = (int*)alloc(N_NODES * 4);
    int*   row_start = (int*)alloc((N_NODES + 1) * 4);
    int*   rank      = (int*)alloc(N_EDGES * 4);
    int*   csr_src   = (int*)alloc(N_EDGES * 4);
    int*   bsum      = (int*)alloc(64 * 4);
    int*   boff      = (int*)alloc(64 * 4);
    float* logsum    = (float*)alloc(16);
    float* inv_deg   = (float*)alloc(N_NODES * 4);
    float* ampv      = (float*)alloc(N_NODES * 4);
    float* attv      = (float*)alloc(N_NODES * 4);
    float* p         = (float*)alloc((size_t)N_NODES * 64 * 4);
    float* q         = (float*)alloc((size_t)N_NODES * 64 * 4);
    float* aggr      = (float*)alloc((size_t)N_NODES * 256 * 4);
    float* xb0       = (float*)alloc((size_t)N_NODES * 64 * 4);
    float* xb1       = (float*)alloc((size_t)N_NODES * 64 * 4);
    float* g_sum     = (float*)alloc(64 * 64 * 4);
    u16*   WkS       = (u16*)alloc((size_t)3 * WKS_LAYER * 2);
    u16*   PreS      = (u16*)alloc((size_t)3 * PRES_LAYER * 2);
    float* bcv       = (float*)alloc(3 * 64 * 4);

    // weight folding + pre_w split + workspace/accumulator zero-init
    k_comb<<<721, 256, 0, stream>>>(post_w, lin_w, pre_w, post_b, lin_b,
                                    WkS, PreS, bcv, cnt, logsum, g_sum);

    k_count<<<(N_EDGES + 255) / 256, 256, 0, stream>>>(dst, cnt, rank);
    k_chunk_sums<<<NCHUNKS, 256, 0, stream>>>(cnt, bsum, logsum);
    k_scan_top<<<1, 64, 0, stream>>>(bsum, boff, row_start);
    k_scan_chunks<<<NCHUNKS, 256, 0, stream>>>(cnt, boff, row_start);
    k_scatter<<<(N_EDGES + 255) / 256, 256, 0, stream>>>(src, dst, rank,
                                                         row_start, csr_src);
    k_scal<<<(N_NODES + 255) / 256, 256, 0, stream>>>(cnt, logsum, inv_deg,
                                                      ampv, attv);

    const int PRE_BLOCKS  = (N_NODES + 63) / 64;   // 782
    const int POST_BLOCKS = 208;                    // 2 N-halves x 98 + 12 idle
    const float* xin = x;
    float* bufs[3] = {xb0, xb1, xb0};
    for (int l = 0; l < NLAYERS; ++l) {
        k_pre<<<PRE_BLOCKS, 256, 0, stream>>>(xin, PreS + (size_t)l * PRES_LAYER,
                                              pre_b + l * 64, p, q);
        k_aggr<<<(N_NODES + 3) / 4, 256, 0, stream>>>(p, q, row_start, csr_src,
                                                      inv_deg, aggr);
        float* xo = bufs[l];
        const int* bptr = (l == NLAYERS - 1) ? batch : nullptr;
        k_post<<<POST_BLOCKS, 1024, KPOST_LDS_BYTES, stream>>>(
            xin, aggr, ampv, attv, WkS + (size_t)l * WKS_LAYER,
            bcv + l * 64, xo, bptr, g_sum);
        xin = xo;
    }

    k_mlp<<<1, 256, 0, stream>>>(g_sum, batch, mlp_w1, mlp_b1, mlp_w2, mlp_b2,
                                 (float*)d_out);
}